// Round 4
// baseline (744.179 us; speedup 1.0000x reference)
//
#include <hip/hip_runtime.h>

// Problem constants (match reference)
#define NB   4096      // batch
#define NT   256       // steps
#define ND   64        // state dim

// ---------------- cross-lane helpers ----------------
// DPP with full masks + bound_ctrl=1 (all lanes written -> fold-eligible)
template <int CTRL>
__device__ __forceinline__ float dppf(float x) {
  return __int_as_float(__builtin_amdgcn_update_dpp(
      0, __float_as_int(x), CTRL, 0xF, 0xF, true));
}

// EXACT exchange with lane^16 partner, on the VALU pipe (no DS round trip).
// HW-verified fact (round 1 passed, absmax 0): for r = permlane16_swap(v,v),
// r[0]+r[1] == v + v[lane^16] exactly for every lane and arbitrary v, which
// implies {r[0],r[1]} == {v, v[lane^16]} as a multiset per lane. Hence
// selecting the element != v yields the partner exactly (numeric-equality
// cases are value-identical either way). Fallback: ds_swizzle xor-16.
__device__ __forceinline__ float xchg16(float v) {
#if __has_builtin(__builtin_amdgcn_permlane16_swap)
  auto r = __builtin_amdgcn_permlane16_swap(__float_as_int(v), __float_as_int(v),
                                            false, false);
  const float a = __int_as_float((int)r[0]);
  const float b = __int_as_float((int)r[1]);
  return (a == v) ? b : a;
#else
  return __int_as_float(__builtin_amdgcn_ds_swizzle(__float_as_int(v), 0x401F));
#endif
}

// max over 8-lane groups: quad_perm(1,0,3,2), quad_perm(2,3,0,1), row_half_mirror
__device__ __forceinline__ float max8(float x) {
  float t = fmaxf(x, dppf<0xB1>(x));
  t = fmaxf(t, dppf<0x4E>(t));
  t = fmaxf(t, dppf<0x141>(t));
  return t;
}

// Full k=32 dot product for the lane's owned neuron:
//   sum_r v_rot(r)*wo[r]  (own 16-row, DPP row_ror)  +  sum_r vB_rot(r)*wx[r]
// 4 independent 8-deep fmac chains for ILP.
__device__ __forceinline__ float mac32(float v, float vB,
                                       const float wo[16], const float wx[16],
                                       float init) {
  float c0 = fmaf(v, wo[0], init);
  float c1 = dppf<0x121>(v) * wo[1];
  float d0 = vB * wx[0];
  float d1 = dppf<0x121>(vB) * wx[1];
  c0 = fmaf(dppf<0x122>(v),  wo[2],  c0);
  c1 = fmaf(dppf<0x123>(v),  wo[3],  c1);
  d0 = fmaf(dppf<0x122>(vB), wx[2],  d0);
  d1 = fmaf(dppf<0x123>(vB), wx[3],  d1);
  c0 = fmaf(dppf<0x124>(v),  wo[4],  c0);
  c1 = fmaf(dppf<0x125>(v),  wo[5],  c1);
  d0 = fmaf(dppf<0x124>(vB), wx[4],  d0);
  d1 = fmaf(dppf<0x125>(vB), wx[5],  d1);
  c0 = fmaf(dppf<0x126>(v),  wo[6],  c0);
  c1 = fmaf(dppf<0x127>(v),  wo[7],  c1);
  d0 = fmaf(dppf<0x126>(vB), wx[6],  d0);
  d1 = fmaf(dppf<0x127>(vB), wx[7],  d1);
  c0 = fmaf(dppf<0x128>(v),  wo[8],  c0);
  c1 = fmaf(dppf<0x129>(v),  wo[9],  c1);
  d0 = fmaf(dppf<0x128>(vB), wx[8],  d0);
  d1 = fmaf(dppf<0x129>(vB), wx[9],  d1);
  c0 = fmaf(dppf<0x12A>(v),  wo[10], c0);
  c1 = fmaf(dppf<0x12B>(v),  wo[11], c1);
  d0 = fmaf(dppf<0x12A>(vB), wx[10], d0);
  d1 = fmaf(dppf<0x12B>(vB), wx[11], d1);
  c0 = fmaf(dppf<0x12C>(v),  wo[12], c0);
  c1 = fmaf(dppf<0x12D>(v),  wo[13], c1);
  d0 = fmaf(dppf<0x12C>(vB), wx[12], d0);
  d1 = fmaf(dppf<0x12D>(vB), wx[13], d1);
  c0 = fmaf(dppf<0x12E>(v),  wo[14], c0);
  c1 = fmaf(dppf<0x12F>(v),  wo[15], c1);
  d0 = fmaf(dppf<0x12E>(vB), wx[14], d0);
  d1 = fmaf(dppf<0x12F>(vB), wx[15], d1);
  return (c0 + c1) + (d0 + d1);
}

// ===================== Kernel A =====================
// h1pre[b][t][j] = states[b][t][:] . W1[0:64][j] + b1[j]  -> written into `out`.
// 1 row/thread; kc loop NOT unrolled so the ~4.5 KB body stays I$-resident.
__global__ __launch_bounds__(256)
void h1pre_kernel(const float* __restrict__ S,
                  const float* __restrict__ W1,
                  const float* __restrict__ b1,
                  float* __restrict__ out) {
  const size_t row = (size_t)blockIdx.x * 256 + threadIdx.x;   // 0 .. B*T-1
  const float4* srow = (const float4*)(S + row * ND);

  float acc[32];
#pragma unroll
  for (int j = 0; j < 32; ++j) acc[j] = b1[j];                 // uniform -> s_load

#pragma unroll 1
  for (int kc = 0; kc < 4; ++kc) {                             // resident loop body
    float4 x[4];
#pragma unroll
    for (int i = 0; i < 4; ++i) x[i] = srow[kc * 4 + i];
#pragma unroll
    for (int i = 0; i < 4; ++i) {
      const float xv[4] = {x[i].x, x[i].y, x[i].z, x[i].w};
#pragma unroll
      for (int kk = 0; kk < 4; ++kk) {
        const int k = kc * 16 + i * 4 + kk;
#pragma unroll
        for (int j = 0; j < 32; ++j)
          acc[j] = fmaf(xv[kk], W1[k * 32 + j], acc[j]);       // uniform -> s_load
      }
    }
  }

  float4* orow = (float4*)(out + row * 32);
#pragma unroll
  for (int q = 0; q < 8; ++q)
    orow[q] = make_float4(acc[4*q], acc[4*q+1], acc[4*q+2], acc[4*q+3]);
}

// ===================== Kernel B =====================
// 2 batches per wave, 32 lanes per batch, lane owns ONE full neuron l = lane&31.
// Serial-path structure (per step): zero DS-pipe ops.
//   L1: carry v=y AND partner vB=yB both known from the previous epilogue's
//       ballot (yB computed locally: partner's 8-bit group field is
//       (bl >> (sh^16)) & 255 with identical my) -> d-chains start immediately.
//   L2/L3: partner image via VALU v_permlane16_swap select (exact; see xchg16).
//   Epilogue: max8 + 64-bit ballot serves both batches; y and yB derived
//       from the same mask.
// 2048 waves -> 2 waves/SIMD (grid-limited); distance-2 load pipeline covers
// HBM latency on the h1pre/gumbel streams.
__global__ __launch_bounds__(256, 2)
void rec_kernel(const float* __restrict__ G,   // gumbel  [B][T][32]
                const float* __restrict__ W1,  // [96][32] (rows 64..95 used)
                const float* __restrict__ W2,  // [32][32]
                const float* __restrict__ b2,  // [32]
                const float* __restrict__ W3,  // [32][32]
                const float* __restrict__ b3,  // [32]
                float* __restrict__ out) {     // in: h1pre, out: y  [B][T][32]
  const int tid  = threadIdx.x;
  const int wave = tid >> 6;
  const int lane = tid & 63;
  const int half = lane >> 5;            // batch-within-wave
  const int l    = lane & 31;            // owned neuron (column)
  const int s    = lane & 15;
  const int rw   = (lane >> 4) & 1;      // own k-row (16-block own-row DPP covers)
  const int b    = (blockIdx.x * 4 + wave) * 2 + half;

  // rotation-ordered weights: own-row block and other-row (xor-16) block
  float w1o[16], w1x[16], w2o[16], w2x[16], w3o[16], w3x[16];
#pragma unroll
  for (int r = 0; r < 16; ++r) {
    const int kO = ((s - r) & 15) + 16 * rw;
    const int kX = ((s - r) & 15) + 16 * (1 - rw);
    w1o[r] = W1[(64 + kO) * 32 + l];
    w1x[r] = W1[(64 + kX) * 32 + l];
    w2o[r] = W2[kO * 32 + l];
    w2x[r] = W2[kX * 32 + l];
    w3o[r] = W3[kO * 32 + l];
    w3x[r] = W3[kX * 32 + l];
  }
  const float b2l = b2[l];
  const float b3l = b3[l];

  // carry: v = c0[l] = 1 iff l%8==0. Partner column l^16 has the same l&7,
  // so the initial partner image vB equals v.
  float v  = ((l & 7) == 0) ? 1.f : 0.f;
  float vB = v;

  // distance-2 software pipeline on per-lane column l of h1pre/gumbel
  const size_t base = ((size_t)b * NT) * 32 + l;
  float hA = out[base], hB = out[base + 32];
  float gA = G[base],   gB = G[base + 32];

  const int sh  = lane & 56;
  const int shB = sh ^ 16;               // partner's ballot field offset
  const int my  = lane & 7;

#pragma unroll 1
  for (int t = 0; t < NT; ++t) {
    const int tp = (t + 2 < NT) ? t + 2 : NT - 1;
    const float hC = out[base + (size_t)tp * 32];
    const float gC = G[base + (size_t)tp * 32];

    // L1: q_l = h1pre_l + c . W1[64:96][:,l]   (v, vB both ready at step start)
    float p = mac32(v, vB, w1o, w1x, hA);
    v  = fmaxf(p, 0.f);

    // L2
    vB = xchg16(v);                      // VALU permlane, exact
    p  = mac32(v, vB, w2o, w2x, b2l);
    v  = fmaxf(p, 0.f);

    // L3 (+ gumbel; tau=1>0 monotone, softmax skipped)
    vB = xchg16(v);
    const float q = mac32(v, vB, w3o, w3x, b3l + gA);

    // argmax over 8-lane groups (= cd=8 categories); 64-bit ballot covers
    // both batches; first-max tie-break matches np.argmax
    const float m = max8(q);
    const unsigned long long bl = __ballot(q == m);
    const unsigned gr  = (unsigned)(bl >> sh)  & 255u;
    const unsigned grB = (unsigned)(bl >> shB) & 255u;
    const float y  = ((__ffs(gr)  - 1) == my) ? 1.f : 0.f;
    const float yB = ((__ffs(grB) - 1) == my) ? 1.f : 0.f;

    out[base + (size_t)t * 32] = y;      // all 64 lanes useful, coalesced

    v  = y;                              // lane-local carry
    vB = yB;                             // partner carry, computed locally

    hA = hB; hB = hC; gA = gB; gB = gC;
  }
}

extern "C" void kernel_launch(void* const* d_in, const int* in_sizes, int n_in,
                              void* d_out, int out_size, void* d_ws, size_t ws_size,
                              hipStream_t stream) {
  const float* S  = (const float*)d_in[0];
  const float* G  = (const float*)d_in[1];
  // d_in[2] = tau (==1.0; argmax invariant for any tau>0 -> unused)
  const float* W1 = (const float*)d_in[3];
  const float* b1 = (const float*)d_in[4];
  const float* W2 = (const float*)d_in[5];
  const float* b2 = (const float*)d_in[6];
  const float* W3 = (const float*)d_in[7];
  const float* b3 = (const float*)d_in[8];
  float* out = (float*)d_out;

  // Kernel A: h1pre -> out. 1 row/thread, B*T threads.
  hipLaunchKernelGGL(h1pre_kernel, dim3((NB * NT) / 256), dim3(256), 0, stream,
                     S, W1, b1, out);
  // Kernel B: recurrence, in-place on out. 2 batches/wave -> 512 blocks,
  // 2048 waves = 2 waves/SIMD.
  hipLaunchKernelGGL(rec_kernel, dim3(NB / 8), dim3(256), 0, stream,
                     G, W1, W2, b2, W3, b3, out);
}